// Round 4
// baseline (780.370 us; speedup 1.0000x reference)
//
#include <hip/hip_runtime.h>
#include <hip/hip_bf16.h>
#include <cstdint>

// Problem constants (fixed-shape problem)
constexpr int NT   = 8192;
constexpr int H    = 1024;
constexpr int FFN  = 4096;
constexpr int E    = 8;
constexpr int M    = NT * 2;     // 16384 dispatched rows (topk=2)
constexpr int CAP  = M / E;      // 2048 rows per expert

typedef unsigned short u16;
typedef short short8 __attribute__((ext_vector_type(8)));
typedef float f32x4 __attribute__((ext_vector_type(4)));

__device__ __forceinline__ u16 f2bf(float f) {
  union { float f; unsigned u; } c{f};
  unsigned r = (c.u + 0x7FFFu + ((c.u >> 16) & 1u)) >> 16;  // RNE
  return (u16)r;
}
__device__ __forceinline__ float bf2f(u16 u) {
  union { unsigned u; float f; } c{((unsigned)u) << 16};
  return c.f;
}
// async global->LDS direct copy, 16B per lane. LDS dest = wave-uniform base + lane*16.
__device__ __forceinline__ void async16(const void* g, void* l) {
  auto gp = reinterpret_cast<const __attribute__((address_space(1))) unsigned*>(
      reinterpret_cast<uintptr_t>(g));
  auto lp = reinterpret_cast<__attribute__((address_space(3))) unsigned*>(
      reinterpret_cast<uintptr_t>(l));
  __builtin_amdgcn_global_load_lds(gp, lp, 16, 0, 0);
}

// tanh-GELU via sigmoid identity: gelu(x) ~= x * sigmoid(2a(x + b x^3)).
__device__ __forceinline__ float gelu_fast(float x) {
  const float u = x * x;
  const float w = x * (-2.30220795f + -0.102943895f * u);
  return x * __frcp_rn(1.0f + exp2f(w));
}

// ---------- transpose tile body: W [E][K][N] fp32 -> WT [E][N][K] bf16 ------
__device__ __forceinline__ void transpose_body(const float* __restrict__ W,
                                               u16* __restrict__ WT,
                                               int K, int N, int tb,
                                               float (*tile)[65]) {
  const int ntx = N >> 6;
  const int per = ntx * (K >> 6);
  const int e   = tb / per;
  const int rem = tb - e * per;
  const int bx  = rem % ntx;
  const int by  = rem / ntx;
  const float* Wp = W + (size_t)e * K * N;
  u16* Tp = WT + (size_t)e * K * N;
  const int k0 = by * 64, n0 = bx * 64;
  const int tid = threadIdx.x;

  const int u = tid & 15, krb = tid >> 4;
#pragma unroll
  for (int p = 0; p < 4; ++p) {
    const int kr = p * 16 + krb;
    float4 v = *(const float4*)&Wp[(size_t)(k0 + kr) * N + n0 + u * 4];
    tile[kr][u * 4 + 0] = v.x;
    tile[kr][u * 4 + 1] = v.y;
    tile[kr][u * 4 + 2] = v.z;
    tile[kr][u * 4 + 3] = v.w;
  }
  __syncthreads();

  const int n = tid >> 3, cb = tid & 7;
#pragma unroll
  for (int p = 0; p < 2; ++p) {
    const int nn = p * 32 + n;
    u16 pack[8];
#pragma unroll
    for (int j = 0; j < 8; ++j) pack[j] = f2bf(tile[cb * 8 + j][nn]);
    *(short8*)&Tp[(size_t)(n0 + nn) * K + k0 + cb * 8] = *(short8*)pack;
  }
}

// ---------- scatter kernel: 4 tokens per block, 16B stores ----------
__global__ __launch_bounds__(256)
void scatter_kernel(const float* __restrict__ x,
                    const int* __restrict__ sidx,
                    u16* __restrict__ disp) {
  const int b = blockIdx.x;
  const int tid = threadIdx.x;
  const int half = tid >> 7;
  const int r = tid & 127;
#pragma unroll
  for (int it = 0; it < 2; ++it) {
    const int t = it * 4096 + b * 2 + half;
    const int r0 = sidx[2 * t + 0];
    const int r1 = sidx[2 * t + 1];
    const float4* xr = (const float4*)(x + (size_t)t * H);
    float4 v0 = xr[r * 2 + 0];
    float4 v1 = xr[r * 2 + 1];
    u16 pk[8] = {f2bf(v0.x), f2bf(v0.y), f2bf(v0.z), f2bf(v0.w),
                 f2bf(v1.x), f2bf(v1.y), f2bf(v1.z), f2bf(v1.w)};
    *(short8*)&disp[(size_t)r0 * H + r * 8] = *(short8*)pk;
    *(short8*)&disp[(size_t)r1 * H + r * 8] = *(short8*)pk;
  }
}

// ---------- standalone transpose kernel ----------
__global__ __launch_bounds__(256)
void transpose_cvt_kernel(const float* __restrict__ W, u16* __restrict__ WT,
                          int K, int N) {
  __shared__ float tile[64][65];
  transpose_body(W, WT, K, N, blockIdx.x, tile);
}

// ======================================================================
// GEMM: 256x256 tile, BK=64, 8 waves (2Mx4N), 8-phase counted-vmcnt pipeline,
// PERSISTENT blocks: each block runs NSEG output tiles (same A row-panel,
// consecutive tn) as ONE continuous virtual K-loop of TT = NSEG*KT K-tiles.
// The stage stream / buffer parity / vmcnt(6) counting continue across
// segment boundaries; the per-segment epilogue runs while the next
// segment's 6 prefetch loads are in flight (hidden under load latency).
//
// Phase reads (tile gt; LDS row == global tile row):
//   P0: A[0,64)u[128,192)   B[0,32)u[64,96)u[128,160)u[192,224)
//   P1: B[32,64)u[96,128)u[160,192)u[224,256)
//   P2: A[64,128)u[192,256)
//   P3: (registers only)
// Stage units (idx = n&3): 0 A_h0 (read P0) | 1 B_h0 (read P0)
//                          2 A_h1 (read P2) | 3 B_h1 (read P1)
// Per-tile issue slots (stage n = 4*gt+7 .. 4*gt+10):
//   P0: B_h1(gt+1) other buffer | P1: A_h0(gt+2) cur buf after last read P0
//   P2: B_h0(gt+2) after P0     | P3: A_h1(gt+2) after P2      -- all safe
// vmcnt(6) at tile boundary => tile gt+1 fully landed, 6 loads in flight.
// ======================================================================
template <bool GELU, int KTLOG, int NSEG>
__global__ __launch_bounds__(512, 2)
void gemm_bt_kernel(const u16* __restrict__ A,   // [E][Mn][Kn]
                    const u16* __restrict__ Bt,  // [E][Nn][Kn]
                    u16* __restrict__ C,         // [E][Mn][Nn]
                    int Mn, int Nn, int Kn) {
  __shared__ __align__(16) u16 lA[2 * 16384];
  __shared__ __align__(16) u16 lB[2 * 16384];

  constexpr int KT = 1 << KTLOG;
  constexpr int TT = NSEG * KT;

  const int b = blockIdx.x;
  const int e = b & 7;                 // XCD pinning: expert e -> XCD e
  const int p = b >> 3;                // [0,32) per expert
  const int tm  = p & 7;               // A row-panel (fixed per block)
  const int tn0 = (p >> 3) * NSEG;     // first B col-panel
  const int m0 = tm * 256;

  const u16* __restrict__ Ae = A  + (size_t)e * Mn * Kn + (size_t)m0 * Kn;
  const u16* __restrict__ Be = Bt + (size_t)e * Nn * Kn + (size_t)tn0 * 256 * Kn;
  u16* __restrict__ Ce = C + (size_t)e * Mn * Nn;

  const int tid  = threadIdx.x;
  const int lane = tid & 63;
  const int wave = tid >> 6;
  const int wr = wave >> 2, wc = wave & 3;
  const int llo = lane & 15, lhi = lane >> 4, lsw = llo & 7;

  // XOR chunk swizzle: LDS[row][c] = G[row][c ^ (row&7)]; row&7 == (tid>>3)&7
  const int gcol = ((tid & 7) ^ ((tid >> 3) & 7)) * 8;
  const int rowA = tid >> 3;                                    // [0,64)
  const int rowB = (wave >> 2) * 64 + (wave & 3) * 8 + ((tid >> 3) & 7);
  const u16* pA = Ae + (size_t)rowA * Kn + gcol;
  const u16* pB = Be + (size_t)rowB * Kn + gcol;
  const int ldA = wave * 8 * 64;                                // wave-uniform
  const int ldB = ((wave >> 2) * 64 + (wave & 3) * 8) * 64;     // wave-uniform

  // LDS read offsets (u16)
  const int arow0 = (wr * 128 + llo) * 64;
  const int brow0 = (wc * 64 + llo) * 64;
  const int ck0 = (lhi ^ lsw) * 8;
  const int ck1 = ((lhi + 4) ^ lsw) * 8;

  auto stage = [&](int n) {
    if (n >= 4 * TT) return;
    const int gt  = n >> 2, idx = n & 3;
    const int seg = gt >> KTLOG;
    const int kofs = (gt & (KT - 1)) << 6;
    const int bsel = (gt & 1) << 14;
    const int h = idx >> 1;
    if ((idx & 1) == 0) {  // A: rows h*64 + {[0,64), [128,192)}
      const u16* sp = pA + (size_t)(h * 64) * Kn + kofs;
      u16* dp = lA + bsel + h * (64 * 64) + ldA;
      async16(sp, dp);
      async16(sp + (size_t)128 * Kn, dp + 128 * 64);
    } else {               // B: rows h*32 + per-wave stripes, seg-dependent cols
      const u16* sp = pB + (size_t)seg * 256 * (size_t)Kn +
                      (size_t)(h * 32) * Kn + kofs;
      u16* dp = lB + bsel + h * (32 * 64) + ldB;
      async16(sp, dp);
      async16(sp + (size_t)128 * Kn, dp + 128 * 64);
    }
  };

  f32x4 acc[8][4] = {};
  short8 aA[4][2], b0f[2][2], b1f[2][2];

  auto epilogue = [&](int seg) {
    const int n0 = (tn0 + seg) * 256;
#pragma unroll
    for (int mi = 0; mi < 8; ++mi) {
      const int mrow = m0 + wr * 128 + mi * 16 + lhi * 4;
#pragma unroll
      for (int nj = 0; nj < 4; ++nj) {
        const int ncol = n0 + wc * 64 + nj * 16 + llo;
#pragma unroll
        for (int r = 0; r < 4; ++r) {
          float v = acc[mi][nj][r];
          if (GELU) v = gelu_fast(v);
          Ce[(size_t)(mrow + r) * Nn + ncol] = f2bf(v);
        }
      }
    }
    const f32x4 z = {0.f, 0.f, 0.f, 0.f};
#pragma unroll
    for (int mi = 0; mi < 8; ++mi)
#pragma unroll
      for (int nj = 0; nj < 4; ++nj) acc[mi][nj] = z;
  };

  // prologue: n=0..6 = tile0{A_h0,B_h0,A_h1,B_h1} + tile1{A_h0,B_h0,A_h1}
#pragma unroll
  for (int n = 0; n < 7; ++n) stage(n);
  asm volatile("s_waitcnt vmcnt(6)" ::: "memory");
  __builtin_amdgcn_s_barrier();

#pragma unroll 1
  for (int gt = 0; gt < TT; ++gt) {
    const u16* bA = &lA[(gt & 1) << 14];
    const u16* bB = &lB[(gt & 1) << 14];
    const int g = 4 * gt;

    // ---- P0: ds-read A quads 0-3 (8) + B duo 0-1 (4); stage B_h1(gt+1); MFMA (M0,N0)
#pragma unroll
    for (int mi = 0; mi < 4; ++mi) {
      aA[mi][0] = *(const short8*)&bA[arow0 + mi * 1024 + ck0];
      aA[mi][1] = *(const short8*)&bA[arow0 + mi * 1024 + ck1];
    }
#pragma unroll
    for (int nj = 0; nj < 2; ++nj) {
      b0f[nj][0] = *(const short8*)&bB[brow0 + nj * 1024 + ck0];
      b0f[nj][1] = *(const short8*)&bB[brow0 + nj * 1024 + ck1];
    }
    stage(g + 7);
    asm volatile("s_waitcnt lgkmcnt(8)" ::: "memory");
    __builtin_amdgcn_s_barrier();
    asm volatile("s_waitcnt lgkmcnt(0)" ::: "memory");
    __builtin_amdgcn_s_setprio(1);
#pragma unroll
    for (int mi = 0; mi < 4; ++mi)
#pragma unroll
      for (int nj = 0; nj < 2; ++nj)
#pragma unroll
        for (int ks = 0; ks < 2; ++ks)
          acc[mi][nj] = __builtin_amdgcn_mfma_f32_16x16x32_bf16(
              aA[mi][ks], b0f[nj][ks], acc[mi][nj], 0, 0, 0);
    __builtin_amdgcn_s_setprio(0);
    __builtin_amdgcn_s_barrier();

    // ---- P1: ds-read B duo 2-3 (4); stage A_h0(gt+2); MFMA (M0,N1)
#pragma unroll
    for (int nj = 0; nj < 2; ++nj) {
      b1f[nj][0] = *(const short8*)&bB[brow0 + (nj + 2) * 1024 + ck0];
      b1f[nj][1] = *(const short8*)&bB[brow0 + (nj + 2) * 1024 + ck1];
    }
    stage(g + 8);
    __builtin_amdgcn_s_barrier();
    asm volatile("s_waitcnt lgkmcnt(0)" ::: "memory");
    __builtin_amdgcn_s_setprio(1);
#pragma unroll
    for (int mi = 0; mi < 4; ++mi)
#pragma unroll
      for (int nj = 0; nj < 2; ++nj)
#pragma unroll
        for (int ks = 0; ks < 2; ++ks)
          acc[mi][nj + 2] = __builtin_amdgcn_mfma_f32_16x16x32_bf16(
              aA[mi][ks], b1f[nj][ks], acc[mi][nj + 2], 0, 0, 0);
    __builtin_amdgcn_s_setprio(0);
    __builtin_amdgcn_s_barrier();

    // ---- P2: ds-read A quads 4-7 (8, overwrites aA); stage B_h0(gt+2); MFMA (M1,N1)
#pragma unroll
    for (int mi = 0; mi < 4; ++mi) {
      aA[mi][0] = *(const short8*)&bA[arow0 + (mi + 4) * 1024 + ck0];
      aA[mi][1] = *(const short8*)&bA[arow0 + (mi + 4) * 1024 + ck1];
    }
    stage(g + 9);
    __builtin_amdgcn_s_barrier();
    asm volatile("s_waitcnt lgkmcnt(0)" ::: "memory");
    __builtin_amdgcn_s_setprio(1);
#pragma unroll
    for (int mi = 0; mi < 4; ++mi)
#pragma unroll
      for (int nj = 0; nj < 2; ++nj)
#pragma unroll
        for (int ks = 0; ks < 2; ++ks)
          acc[mi + 4][nj + 2] = __builtin_amdgcn_mfma_f32_16x16x32_bf16(
              aA[mi][ks], b1f[nj][ks], acc[mi + 4][nj + 2], 0, 0, 0);
    __builtin_amdgcn_s_setprio(0);
    __builtin_amdgcn_s_barrier();

    // ---- P3: no ds-reads (b0f reg-held); stage A_h1(gt+2); MFMA (M1,N0)
    stage(g + 10);
    __builtin_amdgcn_s_barrier();
    __builtin_amdgcn_s_setprio(1);
#pragma unroll
    for (int mi = 0; mi < 4; ++mi)
#pragma unroll
      for (int nj = 0; nj < 2; ++nj)
#pragma unroll
        for (int ks = 0; ks < 2; ++ks)
          acc[mi + 4][nj] = __builtin_amdgcn_mfma_f32_16x16x32_bf16(
              aA[mi][ks], b0f[nj][ks], acc[mi + 4][nj], 0, 0, 0);
    __builtin_amdgcn_s_setprio(0);

    // tile boundary: counted vmcnt (never 0 in steady state)
    if (gt + 2 < TT) {
      asm volatile("s_waitcnt vmcnt(6)" ::: "memory");
      __builtin_amdgcn_s_barrier();
    } else if (gt + 2 == TT) {
      asm volatile("s_waitcnt vmcnt(0)" ::: "memory");
      __builtin_amdgcn_s_barrier();
    }

    // segment end: flush accumulators (next segment's loads already in flight)
    if ((gt & (KT - 1)) == (KT - 1)) epilogue(gt >> KTLOG);
  }
}

// ---------- gather + sum topk -> fp32 out; 16B loads, 4 tokens/block --------
__global__ __launch_bounds__(256)
void gather_sum_kernel(const u16* __restrict__ ye,
                       const int* __restrict__ sidx,
                       float* __restrict__ out) {
  const int tid = threadIdx.x;
  const int half = tid >> 7;
  const int r = tid & 127;
#pragma unroll
  for (int it = 0; it < 2; ++it) {
    const int t = it * 4096 + blockIdx.x * 2 + half;
    const int r0 = sidx[2 * t + 0];
    const int r1 = sidx[2 * t + 1];
    short8 a = *(const short8*)&ye[(size_t)r0 * H + r * 8];
    short8 b = *(const short8*)&ye[(size_t)r1 * H + r * 8];
    float4 s0, s1;
    s0.x = bf2f((u16)a[0]) + bf2f((u16)b[0]);
    s0.y = bf2f((u16)a[1]) + bf2f((u16)b[1]);
    s0.z = bf2f((u16)a[2]) + bf2f((u16)b[2]);
    s0.w = bf2f((u16)a[3]) + bf2f((u16)b[3]);
    s1.x = bf2f((u16)a[4]) + bf2f((u16)b[4]);
    s1.y = bf2f((u16)a[5]) + bf2f((u16)b[5]);
    s1.z = bf2f((u16)a[6]) + bf2f((u16)b[6]);
    s1.w = bf2f((u16)a[7]) + bf2f((u16)b[7]);
    float4* orow = (float4*)(out + (size_t)t * H);
    orow[r * 2 + 0] = s0;
    orow[r * 2 + 1] = s1;
  }
}

extern "C" void kernel_launch(void* const* d_in, const int* in_sizes, int n_in,
                              void* d_out, int out_size, void* d_ws, size_t ws_size,
                              hipStream_t stream) {
  (void)in_sizes; (void)n_in; (void)out_size;
  const float* x    = (const float*)d_in[0];
  const float* w0   = (const float*)d_in[1];
  const float* w1   = (const float*)d_in[2];
  const int*   sidx = (const int*)d_in[3];
  float* out = (float*)d_out;

  // workspace layout (288 MB):
  //   wt0 : W0^T bf16 [E][FFN][H]          64 MB @ 0
  //   wt1 : W1^T bf16 [E][H][FFN]          64 MB @ 64 MB
  //   disp: dispatched bf16 [M][H]         32 MB @ 128 MB (aliased as ye)
  //   mid : gelu(x@W0) bf16 [E][CAP][FFN] 128 MB @ 160 MB
  char* ws = (char*)d_ws;
  const size_t MB = 1024ull * 1024;
  u16* wt0  = (u16*)ws;
  u16* wt1  = (u16*)(ws + 64 * MB);
  u16* disp = (u16*)(ws + 128 * MB);
  u16* mid  = (u16*)(ws + 160 * MB);
  u16* ye   = disp;  // disp dead after gemm0
  const bool roomy = ws_size >= 288 * MB;

  if (roomy) {
    // 1) scatter/cast + W0^T + W1^T (split for per-kernel profiling)
    scatter_kernel<<<2048, 256, 0, stream>>>(x, sidx, disp);
    transpose_cvt_kernel<<<8192, 256, 0, stream>>>(w0, wt0, H, FFN);
    transpose_cvt_kernel<<<8192, 256, 0, stream>>>(w1, wt1, FFN, H);
    // 2) mid = gelu(disp @ W0^T) : 8 experts x (2048x4096x1024), 4 segs/block
    gemm_bt_kernel<true, 4, 4><<<256, 512, 0, stream>>>(disp, wt0, mid, CAP, FFN, H);
    // 3) ye = mid @ W1^T         : 8 experts x (2048x1024x4096), 1 seg/block
    gemm_bt_kernel<false, 6, 1><<<256, 512, 0, stream>>>(mid, wt1, ye, CAP, H, FFN);
  } else {
    // tight ws: wt1 aliases wt0, transpose W1 after gemm0
    wt1 = wt0;
    scatter_kernel<<<2048, 256, 0, stream>>>(x, sidx, disp);
    transpose_cvt_kernel<<<8192, 256, 0, stream>>>(w0, wt0, H, FFN);
    gemm_bt_kernel<true, 4, 4><<<256, 512, 0, stream>>>(disp, wt0, mid, CAP, FFN, H);
    transpose_cvt_kernel<<<8192, 256, 0, stream>>>(w1, wt1, FFN, H);
    gemm_bt_kernel<false, 6, 1><<<256, 512, 0, stream>>>(mid, wt1, ye, CAP, H, FFN);
  }
  // 4) out[t] = ye[s0] + ye[s1]
  gather_sum_kernel<<<2048, 256, 0, stream>>>(ye, sidx, out);
}

// Round 6
// 611.678 us; speedup vs baseline: 1.2758x; 1.2758x over previous
//
#include <hip/hip_runtime.h>
#include <hip/hip_bf16.h>
#include <cstdint>

// Problem constants (fixed-shape problem)
constexpr int NT   = 8192;
constexpr int H    = 1024;
constexpr int FFN  = 4096;
constexpr int E    = 8;
constexpr int M    = NT * 2;     // 16384 dispatched rows (topk=2)
constexpr int CAP  = M / E;      // 2048 rows per expert

typedef unsigned short u16;
typedef short short8 __attribute__((ext_vector_type(8)));
typedef float f32x4 __attribute__((ext_vector_type(4)));

__device__ __forceinline__ u16 f2bf(float f) {
  union { float f; unsigned u; } c{f};
  unsigned r = (c.u + 0x7FFFu + ((c.u >> 16) & 1u)) >> 16;  // RNE
  return (u16)r;
}
__device__ __forceinline__ float bf2f(u16 u) {
  union { unsigned u; float f; } c{((unsigned)u) << 16};
  return c.f;
}
// async global->LDS direct copy, 16B per lane. LDS dest = wave-uniform base + lane*16.
__device__ __forceinline__ void async16(const void* g, void* l) {
  auto gp = reinterpret_cast<const __attribute__((address_space(1))) unsigned*>(
      reinterpret_cast<uintptr_t>(g));
  auto lp = reinterpret_cast<__attribute__((address_space(3))) unsigned*>(
      reinterpret_cast<uintptr_t>(l));
  __builtin_amdgcn_global_load_lds(gp, lp, 16, 0, 0);
}

// tanh-GELU via sigmoid identity: gelu(x) ~= x * sigmoid(2a(x + b x^3)).
__device__ __forceinline__ float gelu_fast(float x) {
  const float u = x * x;
  const float w = x * (-2.30220795f + -0.102943895f * u);
  return x * __frcp_rn(1.0f + exp2f(w));
}

// ---------- transpose tile body: W [E][K][N] fp32 -> WT [E][N][K] bf16 ------
__device__ __forceinline__ void transpose_body(const float* __restrict__ W,
                                               u16* __restrict__ WT,
                                               int K, int N, int tb,
                                               float (*tile)[65]) {
  const int ntx = N >> 6;
  const int per = ntx * (K >> 6);
  const int e   = tb / per;
  const int rem = tb - e * per;
  const int bx  = rem % ntx;
  const int by  = rem / ntx;
  const float* Wp = W + (size_t)e * K * N;
  u16* Tp = WT + (size_t)e * K * N;
  const int k0 = by * 64, n0 = bx * 64;
  const int tid = threadIdx.x;

  const int u = tid & 15, krb = tid >> 4;
#pragma unroll
  for (int p = 0; p < 4; ++p) {
    const int kr = p * 16 + krb;
    float4 v = *(const float4*)&Wp[(size_t)(k0 + kr) * N + n0 + u * 4];
    tile[kr][u * 4 + 0] = v.x;
    tile[kr][u * 4 + 1] = v.y;
    tile[kr][u * 4 + 2] = v.z;
    tile[kr][u * 4 + 3] = v.w;
  }
  __syncthreads();

  const int n = tid >> 3, cb = tid & 7;
#pragma unroll
  for (int p = 0; p < 2; ++p) {
    const int nn = p * 32 + n;
    u16 pack[8];
#pragma unroll
    for (int j = 0; j < 8; ++j) pack[j] = f2bf(tile[cb * 8 + j][nn]);
    *(short8*)&Tp[(size_t)(n0 + nn) * K + k0 + cb * 8] = *(short8*)pack;
  }
}

// ---------- scatter kernel: 4 tokens per block, 16B stores ----------
__global__ __launch_bounds__(256)
void scatter_kernel(const float* __restrict__ x,
                    const int* __restrict__ sidx,
                    u16* __restrict__ disp) {
  const int b = blockIdx.x;
  const int tid = threadIdx.x;
  const int half = tid >> 7;
  const int r = tid & 127;
#pragma unroll
  for (int it = 0; it < 2; ++it) {
    const int t = it * 4096 + b * 2 + half;
    const int r0 = sidx[2 * t + 0];
    const int r1 = sidx[2 * t + 1];
    const float4* xr = (const float4*)(x + (size_t)t * H);
    float4 v0 = xr[r * 2 + 0];
    float4 v1 = xr[r * 2 + 1];
    u16 pk[8] = {f2bf(v0.x), f2bf(v0.y), f2bf(v0.z), f2bf(v0.w),
                 f2bf(v1.x), f2bf(v1.y), f2bf(v1.z), f2bf(v1.w)};
    *(short8*)&disp[(size_t)r0 * H + r * 8] = *(short8*)pk;
    *(short8*)&disp[(size_t)r1 * H + r * 8] = *(short8*)pk;
  }
}

// ---------- standalone transpose kernel ----------
__global__ __launch_bounds__(256)
void transpose_cvt_kernel(const float* __restrict__ W, u16* __restrict__ WT,
                          int K, int N) {
  __shared__ float tile[64][65];
  transpose_body(W, WT, K, N, blockIdx.x, tile);
}

// ======================================================================
// GEMM: 256x256 tile, BK=64, 8 waves (2Mx4N), 8-phase counted-vmcnt pipeline.
// ROUND-2 measured-good configuration (185 us gemm0, MfmaUtil 31.6%):
// one output tile per block, 4x4 supertile order so the ~16 blocks
// co-resident per XCD share a ~256KB sliding K-slice in L2 (4-way reuse)
// -- this L2 sharing is what keeps the 3-half-tile vmcnt(6) lead
// sufficient (round-4 persistent variant broke it: +50% time).
// Only change vs round 2: Kn is compile-time (KN) -> staging address
// multiplies strength-reduced/hoisted.
//
// Phase reads (tile k; LDS row == global tile row):
//   P0: A[0,64)u[128,192)   B[0,32)u[64,96)u[128,160)u[192,224)
//   P1: B[32,64)u[96,128)u[160,192)u[224,256)
//   P2: A[64,128)u[192,256)
//   P3: (registers only)
// Stage units (idx = n&3): 0 A_h0 (read P0) | 1 B_h0 (read P0)
//                          2 A_h1 (read P2) | 3 B_h1 (read P1)
// Per-tile issue slots (stage n = 4k+7 .. 4k+10):
//   P0: B_h1(k+1) other buffer | P1: A_h0(k+2) cur buf after last read P0
//   P2: B_h0(k+2) after P0     | P3: A_h1(k+2) after P2      -- all safe
// vmcnt(6) at tile boundary => tile k+1 fully landed, 6 loads in flight.
// ======================================================================
template <bool GELU, int KN>
__global__ __launch_bounds__(512, 2)
void gemm_bt_kernel(const u16* __restrict__ A,   // [E][Mn][KN]
                    const u16* __restrict__ Bt,  // [E][Nn][KN]
                    u16* __restrict__ C,         // [E][Mn][Nn]
                    int Mn, int Nn, int ny) {
  __shared__ __align__(16) u16 lA[2 * 16384];
  __shared__ __align__(16) u16 lB[2 * 16384];

  const int b = blockIdx.x;
  const int e = b & 7;                 // XCD pinning: expert e -> XCD e
  const int t = b >> 3;
  const int q = t & 15, s = t >> 4;
  const int sy = ny >> 2;
  const int sm = s % sy, sn = s / sy;
  const int tm = sm * 4 + (q & 3), tn = sn * 4 + (q >> 2);
  const int m0 = tm * 256, n0 = tn * 256;

  const u16* __restrict__ Ae = A  + (size_t)e * Mn * KN + (size_t)m0 * KN;
  const u16* __restrict__ Be = Bt + (size_t)e * Nn * KN + (size_t)n0 * KN;
  u16* __restrict__ Ce = C + (size_t)e * Mn * Nn;

  const int tid  = threadIdx.x;
  const int lane = tid & 63;
  const int wave = tid >> 6;
  const int wr = wave >> 2, wc = wave & 3;
  const int llo = lane & 15, lhi = lane >> 4, lsw = llo & 7;

  // XOR chunk swizzle: LDS[row][c] = G[row][c ^ (row&7)]; row&7 == (tid>>3)&7
  const int gcol = ((tid & 7) ^ ((tid >> 3) & 7)) * 8;
  const int rowA = tid >> 3;                                    // [0,64)
  const int rowB = (wave >> 2) * 64 + (wave & 3) * 8 + ((tid >> 3) & 7);
  const u16* pA = Ae + (size_t)rowA * KN + gcol;
  const u16* pB = Be + (size_t)rowB * KN + gcol;
  const int ldA = wave * 8 * 64;                                // wave-uniform
  const int ldB = ((wave >> 2) * 64 + (wave & 3) * 8) * 64;     // wave-uniform

  // LDS read offsets (u16)
  const int arow0 = (wr * 128 + llo) * 64;
  const int brow0 = (wc * 64 + llo) * 64;
  const int ck0 = (lhi ^ lsw) * 8;
  const int ck1 = ((lhi + 4) ^ lsw) * 8;

  constexpr int KT  = KN >> 6;   // K-tiles
  constexpr int KT4 = KN >> 4;   // total half-tile stages

  auto stage = [&](int n) {
    if (n >= KT4) return;
    const int mt = n >> 2, idx = n & 3;
    const int h = idx >> 1;
    const int koff = mt << 6;
    const int bsel = (mt & 1) << 14;
    if ((idx & 1) == 0) {  // A: rows h*64 + {[0,64), [128,192)}
      const u16* sp = pA + (size_t)(h * 64) * KN + koff;
      u16* dp = lA + bsel + h * (64 * 64) + ldA;
      async16(sp, dp);
      async16(sp + (size_t)128 * KN, dp + 128 * 64);
    } else {               // B: rows h*32 + per-wave stripes
      const u16* sp = pB + (size_t)(h * 32) * KN + koff;
      u16* dp = lB + bsel + h * (32 * 64) + ldB;
      async16(sp, dp);
      async16(sp + (size_t)128 * KN, dp + 128 * 64);
    }
  };

  f32x4 acc[8][4] = {};
  short8 aA[4][2], b0f[2][2], b1f[2][2];

  // prologue: n=0..6 = tile0{A_h0,B_h0,A_h1,B_h1} + tile1{A_h0,B_h0,A_h1}
  // vmcnt(6) -> oldest 8 loads (tile 0, 4 stages) landed
#pragma unroll
  for (int n = 0; n < 7; ++n) stage(n);
  asm volatile("s_waitcnt vmcnt(6)" ::: "memory");
  __builtin_amdgcn_s_barrier();

#pragma unroll 1
  for (int k = 0; k < KT; ++k) {
    const u16* bA = &lA[(k & 1) << 14];
    const u16* bB = &lB[(k & 1) << 14];
    const int g = 4 * k;

    // ---- P0: ds-read A quads 0-3 (8) + B duo 0-1 (4); stage B_h1(k+1); MFMA (M0,N0)
#pragma unroll
    for (int mi = 0; mi < 4; ++mi) {
      aA[mi][0] = *(const short8*)&bA[arow0 + mi * 1024 + ck0];
      aA[mi][1] = *(const short8*)&bA[arow0 + mi * 1024 + ck1];
    }
#pragma unroll
    for (int nj = 0; nj < 2; ++nj) {
      b0f[nj][0] = *(const short8*)&bB[brow0 + nj * 1024 + ck0];
      b0f[nj][1] = *(const short8*)&bB[brow0 + nj * 1024 + ck1];
    }
    stage(g + 7);
    asm volatile("s_waitcnt lgkmcnt(8)" ::: "memory");
    __builtin_amdgcn_s_barrier();
    asm volatile("s_waitcnt lgkmcnt(0)" ::: "memory");
    __builtin_amdgcn_s_setprio(1);
#pragma unroll
    for (int mi = 0; mi < 4; ++mi)
#pragma unroll
      for (int nj = 0; nj < 2; ++nj)
#pragma unroll
        for (int ks = 0; ks < 2; ++ks)
          acc[mi][nj] = __builtin_amdgcn_mfma_f32_16x16x32_bf16(
              aA[mi][ks], b0f[nj][ks], acc[mi][nj], 0, 0, 0);
    __builtin_amdgcn_s_setprio(0);
    __builtin_amdgcn_s_barrier();

    // ---- P1: ds-read B duo 2-3 (4); stage A_h0(k+2); MFMA (M0,N1)
#pragma unroll
    for (int nj = 0; nj < 2; ++nj) {
      b1f[nj][0] = *(const short8*)&bB[brow0 + (nj + 2) * 1024 + ck0];
      b1f[nj][1] = *(const short8*)&bB[brow0 + (nj + 2) * 1024 + ck1];
    }
    stage(g + 8);
    __builtin_amdgcn_s_barrier();
    asm volatile("s_waitcnt lgkmcnt(0)" ::: "memory");
    __builtin_amdgcn_s_setprio(1);
#pragma unroll
    for (int mi = 0; mi < 4; ++mi)
#pragma unroll
      for (int nj = 0; nj < 2; ++nj)
#pragma unroll
        for (int ks = 0; ks < 2; ++ks)
          acc[mi][nj + 2] = __builtin_amdgcn_mfma_f32_16x16x32_bf16(
              aA[mi][ks], b1f[nj][ks], acc[mi][nj + 2], 0, 0, 0);
    __builtin_amdgcn_s_setprio(0);
    __builtin_amdgcn_s_barrier();

    // ---- P2: ds-read A quads 4-7 (8, overwrites aA); stage B_h0(k+2); MFMA (M1,N1)
#pragma unroll
    for (int mi = 0; mi < 4; ++mi) {
      aA[mi][0] = *(const short8*)&bA[arow0 + (mi + 4) * 1024 + ck0];
      aA[mi][1] = *(const short8*)&bA[arow0 + (mi + 4) * 1024 + ck1];
    }
    stage(g + 9);
    __builtin_amdgcn_s_barrier();
    asm volatile("s_waitcnt lgkmcnt(0)" ::: "memory");
    __builtin_amdgcn_s_setprio(1);
#pragma unroll
    for (int mi = 0; mi < 4; ++mi)
#pragma unroll
      for (int nj = 0; nj < 2; ++nj)
#pragma unroll
        for (int ks = 0; ks < 2; ++ks)
          acc[mi + 4][nj + 2] = __builtin_amdgcn_mfma_f32_16x16x32_bf16(
              aA[mi][ks], b1f[nj][ks], acc[mi + 4][nj + 2], 0, 0, 0);
    __builtin_amdgcn_s_setprio(0);
    __builtin_amdgcn_s_barrier();

    // ---- P3: no ds-reads (b0f reg-held); stage A_h1(k+2); MFMA (M1,N0)
    stage(g + 10);
    __builtin_amdgcn_s_barrier();
    __builtin_amdgcn_s_setprio(1);
#pragma unroll
    for (int mi = 0; mi < 4; ++mi)
#pragma unroll
      for (int nj = 0; nj < 2; ++nj)
#pragma unroll
        for (int ks = 0; ks < 2; ++ks)
          acc[mi + 4][nj] = __builtin_amdgcn_mfma_f32_16x16x32_bf16(
              aA[mi][ks], b0f[nj][ks], acc[mi + 4][nj], 0, 0, 0);
    __builtin_amdgcn_s_setprio(0);

    // tile boundary: counted vmcnt (never 0 in steady state)
    if (k + 2 < KT) {
      asm volatile("s_waitcnt vmcnt(6)" ::: "memory");
      __builtin_amdgcn_s_barrier();
    } else if (k + 2 == KT) {
      asm volatile("s_waitcnt vmcnt(0)" ::: "memory");
      __builtin_amdgcn_s_barrier();
    }
  }

  // epilogue: C/D layout col=lane&15, row=(lane>>4)*4+reg  [m89-verified]
#pragma unroll
  for (int mi = 0; mi < 8; ++mi) {
    const int mrow = m0 + wr * 128 + mi * 16 + lhi * 4;
#pragma unroll
    for (int nj = 0; nj < 4; ++nj) {
      const int ncol = n0 + wc * 64 + nj * 16 + llo;
#pragma unroll
      for (int r = 0; r < 4; ++r) {
        float v = acc[mi][nj][r];
        if (GELU) v = gelu_fast(v);
        Ce[(size_t)(mrow + r) * Nn + ncol] = f2bf(v);
      }
    }
  }
}

// ---------- gather + sum topk -> fp32 out; 16B loads, 4 tokens/block --------
__global__ __launch_bounds__(256)
void gather_sum_kernel(const u16* __restrict__ ye,
                       const int* __restrict__ sidx,
                       float* __restrict__ out) {
  const int tid = threadIdx.x;
  const int half = tid >> 7;
  const int r = tid & 127;
#pragma unroll
  for (int it = 0; it < 2; ++it) {
    const int t = it * 4096 + blockIdx.x * 2 + half;
    const int r0 = sidx[2 * t + 0];
    const int r1 = sidx[2 * t + 1];
    short8 a = *(const short8*)&ye[(size_t)r0 * H + r * 8];
    short8 b = *(const short8*)&ye[(size_t)r1 * H + r * 8];
    float4 s0, s1;
    s0.x = bf2f((u16)a[0]) + bf2f((u16)b[0]);
    s0.y = bf2f((u16)a[1]) + bf2f((u16)b[1]);
    s0.z = bf2f((u16)a[2]) + bf2f((u16)b[2]);
    s0.w = bf2f((u16)a[3]) + bf2f((u16)b[3]);
    s1.x = bf2f((u16)a[4]) + bf2f((u16)b[4]);
    s1.y = bf2f((u16)a[5]) + bf2f((u16)b[5]);
    s1.z = bf2f((u16)a[6]) + bf2f((u16)b[6]);
    s1.w = bf2f((u16)a[7]) + bf2f((u16)b[7]);
    float4* orow = (float4*)(out + (size_t)t * H);
    orow[r * 2 + 0] = s0;
    orow[r * 2 + 1] = s1;
  }
}

extern "C" void kernel_launch(void* const* d_in, const int* in_sizes, int n_in,
                              void* d_out, int out_size, void* d_ws, size_t ws_size,
                              hipStream_t stream) {
  (void)in_sizes; (void)n_in; (void)out_size;
  const float* x    = (const float*)d_in[0];
  const float* w0   = (const float*)d_in[1];
  const float* w1   = (const float*)d_in[2];
  const int*   sidx = (const int*)d_in[3];
  float* out = (float*)d_out;

  // workspace layout (288 MB):
  //   wt0 : W0^T bf16 [E][FFN][H]          64 MB @ 0
  //   wt1 : W1^T bf16 [E][H][FFN]          64 MB @ 64 MB
  //   disp: dispatched bf16 [M][H]         32 MB @ 128 MB (aliased as ye)
  //   mid : gelu(x@W0) bf16 [E][CAP][FFN] 128 MB @ 160 MB
  char* ws = (char*)d_ws;
  const size_t MB = 1024ull * 1024;
  u16* wt0  = (u16*)ws;
  u16* wt1  = (u16*)(ws + 64 * MB);
  u16* disp = (u16*)(ws + 128 * MB);
  u16* mid  = (u16*)(ws + 160 * MB);
  u16* ye   = disp;  // disp dead after gemm0
  const bool roomy = ws_size >= 288 * MB;

  if (roomy) {
    // 1) scatter/cast + W0^T + W1^T
    scatter_kernel<<<2048, 256, 0, stream>>>(x, sidx, disp);
    transpose_cvt_kernel<<<8192, 256, 0, stream>>>(w0, wt0, H, FFN);
    transpose_cvt_kernel<<<8192, 256, 0, stream>>>(w1, wt1, FFN, H);
    // 2) mid = gelu(disp @ W0^T) : 8 experts x (2048x4096x1024)
    gemm_bt_kernel<true, H><<<1024, 512, 0, stream>>>(disp, wt0, mid, CAP, FFN, CAP / 256);
    // 3) ye = mid @ W1^T         : 8 experts x (2048x1024x4096)
    gemm_bt_kernel<false, FFN><<<256, 512, 0, stream>>>(mid, wt1, ye, CAP, H, CAP / 256);
  } else {
    // tight ws: wt1 aliases wt0, transpose W1 after gemm0
    wt1 = wt0;
    scatter_kernel<<<2048, 256, 0, stream>>>(x, sidx, disp);
    transpose_cvt_kernel<<<8192, 256, 0, stream>>>(w0, wt0, H, FFN);
    gemm_bt_kernel<true, H><<<1024, 512, 0, stream>>>(disp, wt0, mid, CAP, FFN, CAP / 256);
    transpose_cvt_kernel<<<8192, 256, 0, stream>>>(w1, wt1, FFN, H);
    gemm_bt_kernel<false, FFN><<<256, 512, 0, stream>>>(mid, wt1, ye, CAP, H, CAP / 256);
  }
  // 4) out[t] = ye[s0] + ye[s1]
  gather_sum_kernel<<<2048, 256, 0, stream>>>(ye, sidx, out);
}